// Round 8
// baseline (815.936 us; speedup 1.0000x reference)
//
#include <hip/hip_runtime.h>
#include <stdint.h>

// Chamfer distance, B=4, N=M=8192, fp32 [B][N][3], out[B] = d01+d10.
//
// R8: attack the stall decomposition (V=14.7us/sweep vs 6.9 MFMA floor,
// F=11.8us fixed, VGPR_Count=52 => compiler built a zero-lookahead loop):
//  - explicit register prefetch of tile t+2/t+3 B-frags (nv) so the
//    ds_read->mfma latency hides under merge+mfma of tile t;
//  - prep kernel FUSED into the sweep: raw points loaded per pass
//    (issue-early after barrier), fragments built in-register and
//    ds_written to the other LDS buffer after the compute phase;
//    kills a dispatch, a gap, and the efrag global roundtrip;
//  - 2-live-D merge order (fits ~110 VGPR under launch_bounds(256,4),
//    4 blocks/CU); setprio kept; sched_barriers stay out.
// Numerics identical to the verified R2..R7 path (bf16-split K=14 dot,
// d' = q.p - 0.5|p|^2, chunk maxima -> exact fp32 reconstruction).

typedef __bf16 bf16x8 __attribute__((ext_vector_type(8)));
typedef float  f32x16 __attribute__((ext_vector_type(16)));
typedef float  f32x4  __attribute__((ext_vector_type(4)));

constexpr int B     = 4;
constexpr int NPTS  = 8192;
constexpr int BLOCK = 256;
constexpr int QPB   = 256;             // 4 waves * 64 queries
constexpr int QBLKS = NPTS / QPB;      // 32
constexpr int CH    = 4;               // point chunks per (b,dir)
constexpr int CPTS  = NPTS / CH;       // 2048 points per chunk
constexpr int SPTS  = 512;             // points per LDS pass (16 KB/buffer)
constexpr int NPASS = CPTS / SPTS;     // 4
constexpr int TPP   = SPTS / 32;       // 16 tiles per pass
constexpr int RSTRIDE = 36;            // padded f32 per reduce row
constexpr int SMEMB = BLOCK * RSTRIDE * 4;            // 36864 B (>2x16KB)

// ---- fragment builders (same bytes the old prep kernel produced) ----------
// e0(k0-7) = [pxh,pyh,pzh, pxl,pyl,pzl, pxh,pyh]
// e1(k8-15)= [pzh, nh, nl, pxl,pyl,pzl, 0, 0]
__device__ inline bf16x8 mk_e0(float x, float y, float z) {
    __bf16 hx = (__bf16)x, hy = (__bf16)y, hz = (__bf16)z;
    __bf16 lx = (__bf16)(x - (float)hx);
    __bf16 ly = (__bf16)(y - (float)hy);
    __bf16 lz = (__bf16)(z - (float)hz);
    return (bf16x8){hx, hy, hz, lx, ly, lz, hx, hy};
}
__device__ inline bf16x8 mk_e1(float x, float y, float z) {
    __bf16 hx = (__bf16)x, hy = (__bf16)y, hz = (__bf16)z;
    __bf16 lx = (__bf16)(x - (float)hx);
    __bf16 ly = (__bf16)(y - (float)hy);
    __bf16 lz = (__bf16)(z - (float)hz);
    float n = -0.5f * (x * x + y * y + z * z);
    __bf16 nh = (__bf16)n;
    __bf16 nl = (__bf16)(n - (float)nh);
    const __bf16 zb = (__bf16)0.0f;
    return (bf16x8){hz, nh, nl, lx, ly, lz, zb, zb};
}

// ---- Kernel 1: MFMA sweep (prep fused) ------------------------------------
__global__ __launch_bounds__(BLOCK, 4) void chamfer_sweep(
    const float* __restrict__ tpl, const float* __restrict__ src,
    float* __restrict__ cm)                  // [2*B][CH][NPTS] chunk maxima
{
    __shared__ char smem[SMEMB];             // 2x16KB dbuf / 36.9KB reduce

    const int tid = threadIdx.x;
    const int l   = tid & 63;
    const int w   = tid >> 6;
    const int h   = l >> 5;                  // k-group (0: k0-7, 1: k8-15)
    const int r32 = l & 31;                  // A row / B col within tile
    const int c   = blockIdx.z;              // dir*B + b
    const int b   = c & (B - 1);
    const int dir = c >> 2;
    const float* q  = (dir == 0 ? tpl : src) + (size_t)b * NPTS * 3;
    const float* db = (dir == 0 ? src : tpl) + (size_t)b * NPTS * 3;
    const int qbase = blockIdx.x * QPB + w * 64;
    // raw chunk points, as float2 (24B per thread-pair, coalesced)
    const float2* g2 = (const float2*)(db + (size_t)blockIdx.y * CPTS * 3);

    // Issue pass-0 raw loads first; their latency hides under fa build.
    float2 ra = g2[3 * tid], rb = g2[3 * tid + 1], rc = g2[3 * tid + 2];

    // A fragments: row = r32, k = h*8 + e. 64 queries per wave.
    // g0 = [qxh,qyh,qzh, qxh,qyh,qzh, qxl,qyl]; g1 = [qzl,1,1, qxl,qyl,qzl,0,0]
    const __bf16 one = (__bf16)1.0f, zb = (__bf16)0.0f;
    bf16x8 fa[2];
    #pragma unroll
    for (int f = 0; f < 2; ++f) {
        int qi = qbase + f * 32 + r32;
        float x = q[3 * qi], y = q[3 * qi + 1], z = q[3 * qi + 2];
        __bf16 hx = (__bf16)x, hy = (__bf16)y, hz = (__bf16)z;
        __bf16 lx = (__bf16)(x - (float)hx);
        __bf16 ly = (__bf16)(y - (float)hy);
        __bf16 lz = (__bf16)(z - (float)hz);
        if (h == 0) fa[f] = (bf16x8){hx, hy, hz, hx, hy, hz, lx, ly};
        else        fa[f] = (bf16x8){lz, one, one, lx, ly, lz, zb, zb};
    }

    // Build + write pass-0 fragments into buffer 0.
    {
        float4* s4 = (float4*)smem;
        const int base0 = (tid >> 4) * 64 + ((2 * tid) & 31);
        bf16x8 e00 = mk_e0(ra.x, ra.y, rb.x), e10 = mk_e1(ra.x, ra.y, rb.x);
        bf16x8 e01 = mk_e0(rb.y, rc.x, rc.y), e11 = mk_e1(rb.y, rc.x, rc.y);
        s4[base0]      = *(float4*)&e00;
        s4[base0 + 1]  = *(float4*)&e01;
        s4[base0 + 32] = *(float4*)&e10;
        s4[base0 + 33] = *(float4*)&e11;
    }

    f32x16 best0, best1, zc;
    #pragma unroll
    for (int r = 0; r < 16; ++r) { best0[r] = -3.4e38f; best1[r] = -3.4e38f; zc[r] = 0.0f; }

    const int idx0 = h * 32 + r32;           // B-frag index within a tile
    for (int gp = 0; gp < NPASS; ++gp) {
        __syncthreads();                     // buf[gp&1] fully written
        if (gp + 1 < NPASS) {                // issue-early next raw loads
            int fi = 768 * (gp + 1) + 3 * tid;
            ra = g2[fi]; rb = g2[fi + 1]; rc = g2[fi + 2];
        }
        const bf16x8* sb = (const bf16x8*)(smem + (gp & 1) * 16384);
        // Explicit software pipeline: prefetch tiles t+2,t+3 while merging t.
        bf16x8 bv0 = sb[idx0];
        bf16x8 bv1 = sb[64 + idx0];
        __builtin_amdgcn_s_setprio(1);
        #pragma unroll
        for (int t = 0; t < TPP; t += 2) {
            bf16x8 nv0 = sb[(((t + 2) & 15)) * 64 + idx0];
            bf16x8 nv1 = sb[(((t + 3) & 15)) * 64 + idx0];
            f32x16 d0 = __builtin_amdgcn_mfma_f32_32x32x16_bf16(fa[0], bv0, zc, 0, 0, 0);
            f32x16 d1 = __builtin_amdgcn_mfma_f32_32x32x16_bf16(fa[0], bv1, zc, 0, 0, 0);
            #pragma unroll
            for (int r = 0; r < 16; ++r)
                best0[r] = fmaxf(fmaxf(best0[r], d0[r]), d1[r]);   // -> v_max3
            f32x16 e0 = __builtin_amdgcn_mfma_f32_32x32x16_bf16(fa[1], bv0, zc, 0, 0, 0);
            f32x16 e1 = __builtin_amdgcn_mfma_f32_32x32x16_bf16(fa[1], bv1, zc, 0, 0, 0);
            #pragma unroll
            for (int r = 0; r < 16; ++r)
                best1[r] = fmaxf(fmaxf(best1[r], e0[r]), e1[r]);
            bv0 = nv0; bv1 = nv1;
        }
        __builtin_amdgcn_s_setprio(0);
        if (gp + 1 < NPASS) {                // build+write next pass's frags
            float4* s4 = (float4*)(smem + ((gp + 1) & 1) * 16384);
            const int base0 = (tid >> 4) * 64 + ((2 * tid) & 31);
            bf16x8 e00 = mk_e0(ra.x, ra.y, rb.x), e10 = mk_e1(ra.x, ra.y, rb.x);
            bf16x8 e01 = mk_e0(rb.y, rc.x, rc.y), e11 = mk_e1(rb.y, rc.x, rc.y);
            s4[base0]      = *(float4*)&e00;
            s4[base0 + 1]  = *(float4*)&e01;
            s4[base0 + 32] = *(float4*)&e10;
            s4[base0 + 33] = *(float4*)&e11;
        }
    }

    // Epilogue: LDS transpose reduce (no wave shuffles, no atomics).
    // D layout: col = r32, row = (r&3) + 8*(r>>2) + 4*h.
    __syncthreads();                         // all waves done reading sbuf
    float* red = (float*)smem;
    #pragma unroll
    for (int r = 0; r < 16; ++r) {
        int row = (r & 3) + 8 * (r >> 2) + 4 * h;
        red[(w * 64 + row) * RSTRIDE + r32]      = best0[r];
        red[(w * 64 + 32 + row) * RSTRIDE + r32] = best1[r];
    }
    __syncthreads();
    const float* rr = red + tid * RSTRIDE;   // 144B stride: 2-way only (free)
    float m = -3.4e38f;
    #pragma unroll
    for (int j = 0; j < 8; ++j) {
        f32x4 v = *(const f32x4*)(rr + 4 * j);
        m = fmaxf(m, fmaxf(fmaxf(v.x, v.y), fmaxf(v.z, v.w)));
    }
    cm[((size_t)c * CH + blockIdx.y) * NPTS + blockIdx.x * QPB + tid] = m;
}

// ---- Kernel 2: dist = |q|^2 - 2*max_chunks(maxd'), mean, out[b] += --------
__global__ __launch_bounds__(256) void chamfer_final(
    const float* __restrict__ tpl, const float* __restrict__ src,
    const float* __restrict__ cm, float* __restrict__ out)
{
    __shared__ float red[256];
    const int z = blockIdx.x;                // dir*B + b
    const float* qc = (z < B ? tpl : src) + (size_t)(z & (B - 1)) * NPTS * 3;
    const float* cz = cm + (size_t)z * CH * NPTS;

    float s = 0.f;
    for (int i = threadIdx.x; i < NPTS; i += 256) {
        float md = fmaxf(fmaxf(cz[i], cz[NPTS + i]),
                         fmaxf(cz[2 * NPTS + i], cz[3 * NPTS + i]));
        float x = qc[3 * i], y = qc[3 * i + 1], zz = qc[3 * i + 2];
        s += fmaf(md, -2.0f, x * x + y * y + zz * zz);
    }
    red[threadIdx.x] = s;
    __syncthreads();
    #pragma unroll
    for (int off = 128; off > 0; off >>= 1) {
        if (threadIdx.x < off) red[threadIdx.x] += red[threadIdx.x + off];
        __syncthreads();
    }
    if (threadIdx.x == 0)
        atomicAdd(&out[z & (B - 1)], red[0] * (1.0f / NPTS));  // 2 addends/b
}

extern "C" void kernel_launch(void* const* d_in, const int* in_sizes, int n_in,
                              void* d_out, int out_size, void* d_ws, size_t ws_size,
                              hipStream_t stream) {
    const float* tpl = (const float*)d_in[0];
    const float* src = (const float*)d_in[1];
    float* out = (float*)d_out;
    float* cm = (float*)d_ws;                                  // 1 MB

    hipMemsetAsync(d_out, 0x00, (size_t)B * sizeof(float), stream);
    chamfer_sweep<<<dim3(QBLKS, CH, 2 * B), BLOCK, 0, stream>>>(tpl, src, cm);
    chamfer_final<<<2 * B, 256, 0, stream>>>(tpl, src, cm, out);
}